// Round 2
// baseline (268.237 us; speedup 1.0000x reference)
//
#include <hip/hip_runtime.h>
#include <math.h>

#define BN 8
#define CN 64
#define HN 256
#define WN 256
#define HWN (HN * WN)          // 65536
#define NPIX (BN * HWN)        // 524288 pixels (b,h,w)
#define NTOT (BN * CN * HWN)   // 33554432 elements

#define TILE 32                // output tile (TILE x TILE), 256 threads = 8 float4/row
#define GPAD 3                 // halo: 2 (5x5 DoG) + 1 (3x3 Sobel)
#define GDIM (TILE + 2 * GPAD) // 38: gray tile side
#define GLDS 40                // padded LDS row stride for gray
#define DDIM (TILE + 2)        // 34: dog tile side (att halo 1)
#define DLDS 36                // padded LDS row stride for dog

struct DogK { float k[25]; };  // gk1 - gk2, 5x5 row-major

// K1: gray[b,h,w] = mean_c x[b,c,h,w]; float4 across w; channel-swizzled.
__global__ __launch_bounds__(256) void gray_kernel(const float* __restrict__ x,
                                                   float* __restrict__ gray) {
    int idx = blockIdx.x * blockDim.x + threadIdx.x;   // float4-pixel index
    if (idx >= NPIX / 4) return;
    int p4 = idx * 4;
    int b  = p4 / HWN;
    int hw = p4 - b * HWN;
    const float4* xp = (const float4*)(x + (size_t)b * CN * HWN + hw);
    int cs = blockIdx.x & (CN - 1);   // decorrelate channel-stride across blocks
    float4 acc = make_float4(0.f, 0.f, 0.f, 0.f);
    #pragma unroll 8
    for (int i = 0; i < CN; ++i) {
        int c = (i + cs) & (CN - 1);
        float4 v = xp[c * (HWN / 4)];
        acc.x += v.x; acc.y += v.y; acc.z += v.z; acc.w += v.w;
    }
    const float s = 1.0f / (float)CN;
    *(float4*)(gray + p4) = make_float4(acc.x * s, acc.y * s, acc.z * s, acc.w * s);
}

// K2: fused DoG(5x5) -> Sobel -> mag -> sigmoid -> out = x*(1+att), per 32x32 tile.
__global__ __launch_bounds__(256) void fused_kernel(const float* __restrict__ x,
                                                    const float* __restrict__ gray,
                                                    float* __restrict__ out,
                                                    const float* __restrict__ gwp,
                                                    const float* __restrict__ gbp,
                                                    DogK dk) {
    __shared__ float sGray[GDIM * GLDS];
    __shared__ float sDog[DDIM * DLDS];

    int bid = blockIdx.x;
    int b   = bid >> 6;                   // 64 tiles per batch image
    int t   = bid & 63;
    int th0 = (t >> 3) * TILE;            // tile origin (h)
    int tw0 = (t & 7) * TILE;             // tile origin (w)
    int tid = threadIdx.x;

    const float* g = gray + b * HWN;

    // Stage gray tile (38x38) with zero pad outside image.
    for (int i = tid; i < GDIM * GDIM; i += 256) {
        int r = i / GDIM, c = i - r * GDIM;
        int gh = th0 - GPAD + r;
        int gw = tw0 - GPAD + c;
        float v = 0.f;
        if (gh >= 0 && gh < HN && gw >= 0 && gw < WN) v = g[gh * WN + gw];
        sGray[r * GLDS + c] = v;
    }
    __syncthreads();

    // DoG on 34x34 (tile + Sobel halo). Out-of-image dog positions are 0
    // (Sobel zero-pads the *dog array*).
    for (int i = tid; i < DDIM * DDIM; i += 256) {
        int r = i / DDIM, c = i - r * DDIM;
        int gh = th0 - 1 + r;
        int gw = tw0 - 1 + c;
        float v = 0.f;
        if (gh >= 0 && gh < HN && gw >= 0 && gw < WN) {
            float acc = 0.f;
            #pragma unroll
            for (int di = 0; di < 5; ++di)
                #pragma unroll
                for (int dj = 0; dj < 5; ++dj)
                    acc += dk.k[di * 5 + dj] * sGray[(r + di) * GLDS + (c + dj)];
            v = acc;
        }
        sDog[r * DLDS + c] = v;
    }
    __syncthreads();

    // Per-thread: 4 consecutive w pixels (one float4). Sobel + mag + gate.
    int h  = tid >> 3;            // 0..31
    int w4 = (tid & 7) * 4;       // 0,4,...,28
    float gwv = gwp[0], gbv = gbp[0];
    float a[4];
    #pragma unroll
    for (int k = 0; k < 4; ++k) {
        int r = h + 1, c = w4 + k + 1;     // dog LDS coords of center
        float d00 = sDog[(r - 1) * DLDS + (c - 1)];
        float d01 = sDog[(r - 1) * DLDS + (c    )];
        float d02 = sDog[(r - 1) * DLDS + (c + 1)];
        float d10 = sDog[(r    ) * DLDS + (c - 1)];
        float d12 = sDog[(r    ) * DLDS + (c + 1)];
        float d20 = sDog[(r + 1) * DLDS + (c - 1)];
        float d21 = sDog[(r + 1) * DLDS + (c    )];
        float d22 = sDog[(r + 1) * DLDS + (c + 1)];
        float gx = (d02 - d00) + 2.f * (d12 - d10) + (d22 - d20);
        float gy = (d20 - d00) + 2.f * (d21 - d01) + (d22 - d02);
        float mag = sqrtf(gx * gx + gy * gy + 1e-6f);
        float z = mag * gwv + gbv;
        a[k] = 1.f + 1.f / (1.f + expf(-z));   // 1 + sigmoid(z), ALPHA=1
    }
    float4 av = make_float4(a[0], a[1], a[2], a[3]);

    // Apply across all 64 channels: out = x * (1+att). float4, coalesced.
    size_t base = ((size_t)b * CN) * HWN + (size_t)(th0 + h) * WN + (tw0 + w4);
    const float* xb = x + base;
    float* ob = out + base;
    #pragma unroll 4
    for (int c = 0; c < CN; ++c) {
        float4 xv = *(const float4*)(xb + (size_t)c * HWN);
        float4 o  = make_float4(xv.x * av.x, xv.y * av.y, xv.z * av.z, xv.w * av.w);
        *(float4*)(ob + (size_t)c * HWN) = o;
    }
}

extern "C" void kernel_launch(void* const* d_in, const int* in_sizes, int n_in,
                              void* d_out, int out_size, void* d_ws, size_t ws_size,
                              hipStream_t stream) {
    const float* x  = (const float*)d_in[0];
    const float* gw = (const float*)d_in[1];
    const float* gb = (const float*)d_in[2];
    float* out  = (float*)d_out;
    float* gray = (float*)d_ws;   // NPIX floats = 2 MB

    // Host-side DoG taps (pure CPU math; graph-capture safe).
    DogK dk;
    {
        double k1[25], k2[25], s1 = 0.0, s2 = 0.0;
        for (int i = 0; i < 5; ++i) {
            for (int j = 0; j < 5; ++j) {
                double di = i - 2.0, dj = j - 2.0;
                double r2 = di * di + dj * dj;
                k1[i * 5 + j] = exp(-r2 / (2.0 * 1.0 * 1.0));
                k2[i * 5 + j] = exp(-r2 / (2.0 * 2.0 * 2.0));
                s1 += k1[i * 5 + j];
                s2 += k2[i * 5 + j];
            }
        }
        for (int t = 0; t < 25; ++t)
            dk.k[t] = (float)(k1[t] / s1 - k2[t] / s2);
    }

    gray_kernel <<<dim3(NPIX / 4 / 256), dim3(256), 0, stream>>>(x, gray);
    fused_kernel<<<dim3(BN * 64),        dim3(256), 0, stream>>>(x, gray, out, gw, gb, dk);
}